// Round 8
// baseline (372.167 us; speedup 1.0000x reference)
//
#include <hip/hip_runtime.h>
#include <hip/hip_bf16.h>
#include <math.h>

// out[b] = tanh(tanh(dot(x[b,:], w) + b0)), x: [16384, 4096] f32, w: [4096] f32, b: [1] f32
// HBM-bound streamed matvec (AI ~= 0.125 FLOP/B). Roofline: ~262 MB fetch / 6.7 TB/s ~= 40 us.
// 8192 waves; each wave owns rows {gw, gw+8192}, fused in one loop.
// w fragment (16 x f32x4 per lane, row-invariant) hoisted into registers once:
// halves per-row VMEM instructions; 2 independent x streams double MLP.

#define BATCH    16384
#define IN_SIZE  4096
#define VEC4     (IN_SIZE / 4)   // 1024 float4 per row
#define NBLOCKS  2048
#define NWAVES   (NBLOCKS * 4)   // 8192 waves, 2 rows each
#define WREGS    (VEC4 / 64)     // 16 f32x4 of w per lane

typedef float f32x4 __attribute__((ext_vector_type(4)));

__global__ __launch_bounds__(256) void cartnn_matvec_tanh(
    const float* __restrict__ x,
    const float* __restrict__ w,
    const float* __restrict__ b,
    float* __restrict__ out)
{
    const int lane  = threadIdx.x & 63;
    const int gwave = blockIdx.x * 4 + (threadIdx.x >> 6);   // 0..8191
    const f32x4* __restrict__ w4 = reinterpret_cast<const f32x4*>(w);
    const float bias = b[0];

    // Hoist this lane's w fragment into registers (row-invariant): 64 VGPRs.
    f32x4 wreg[WREGS];
    #pragma unroll
    for (int i = 0; i < WREGS; ++i) {
        wreg[i] = w4[lane + 64 * i];
    }

    const int row0 = gwave;             // 0..8191
    const int row1 = gwave + NWAVES;    // 8192..16383
    const f32x4* __restrict__ xa =
        reinterpret_cast<const f32x4*>(x) + (size_t)row0 * VEC4 + lane;
    const f32x4* __restrict__ xb =
        reinterpret_cast<const f32x4*>(x) + (size_t)row1 * VEC4 + lane;

    float acc0 = 0.0f, acc1 = 0.0f;
    #pragma unroll 4
    for (int i = 0; i < WREGS; ++i) {
        f32x4 xv0 = __builtin_nontemporal_load(xa + 64 * i);   // streamed, no reuse
        f32x4 xv1 = __builtin_nontemporal_load(xb + 64 * i);
        f32x4 wv  = wreg[i];
        acc0 = fmaf(xv0.x, wv.x, acc0);
        acc0 = fmaf(xv0.y, wv.y, acc0);
        acc0 = fmaf(xv0.z, wv.z, acc0);
        acc0 = fmaf(xv0.w, wv.w, acc0);
        acc1 = fmaf(xv1.x, wv.x, acc1);
        acc1 = fmaf(xv1.y, wv.y, acc1);
        acc1 = fmaf(xv1.z, wv.z, acc1);
        acc1 = fmaf(xv1.w, wv.w, acc1);
    }

    // Two wave-64 butterfly reductions, interleaved for ILP.
    #pragma unroll
    for (int off = 32; off > 0; off >>= 1) {
        acc0 += __shfl_xor(acc0, off, 64);
        acc1 += __shfl_xor(acc1, off, 64);
    }

    if (lane == 0) {
        out[row0] = tanhf(tanhf(acc0 + bias));
        out[row1] = tanhf(tanhf(acc1 + bias));
    }
}

extern "C" void kernel_launch(void* const* d_in, const int* in_sizes, int n_in,
                              void* d_out, int out_size, void* d_ws, size_t ws_size,
                              hipStream_t stream) {
    const float* x = (const float*)d_in[0];
    const float* w = (const float*)d_in[1];
    const float* b = (const float*)d_in[2];
    float* out = (float*)d_out;

    cartnn_matvec_tanh<<<dim3(NBLOCKS), dim3(256), 0, stream>>>(x, w, b, out);
}

// Round 9
// 333.115 us; speedup vs baseline: 1.1172x; 1.1172x over previous
//
#include <hip/hip_runtime.h>
#include <hip/hip_bf16.h>
#include <math.h>

// out[b] = tanh(tanh(dot(x[b,:], w) + b0)), x: [16384, 4096] f32, w: [4096] f32, b: [1] f32
// HBM-bound streamed matvec. Floor: ~262 MB fetch / 6.7 TB/s ~= 40 us.
// r7 structure (best measured): 8192 waves, 2 sequential rows each, w in-loop (L1),
// nontemporal x loads. NEW vs r7: f32x4 vector accumulation -> v_pk_fma_f32
// (halves FMA issue count; r8 showed the SIMD issue port co-saturates with HBM).
// r8 lesson: do NOT hoist w to registers (64 VGPR -> occupancy halves -> regression).

#define BATCH    16384
#define IN_SIZE  4096
#define VEC4     (IN_SIZE / 4)   // 1024 float4 per row
#define NBLOCKS  2048            // 256 CU x 8 blocks/CU
#define NWAVES   (NBLOCKS * 4)   // 8192 waves, 2 rows each

typedef float f32x4 __attribute__((ext_vector_type(4)));

__global__ __launch_bounds__(256) void cartnn_matvec_tanh(
    const float* __restrict__ x,
    const float* __restrict__ w,
    const float* __restrict__ b,
    float* __restrict__ out)
{
    const int lane  = threadIdx.x & 63;
    const int gwave = blockIdx.x * 4 + (threadIdx.x >> 6);   // 0..8191
    const f32x4* __restrict__ w4 = reinterpret_cast<const f32x4*>(w);
    const float bias = b[0];

    for (int row = gwave; row < BATCH; row += NWAVES) {
        const f32x4* __restrict__ x4 =
            reinterpret_cast<const f32x4*>(x) + (size_t)row * VEC4;

        // 1024 float4 / 64 lanes = 16 loads; 2 independent vector accumulators.
        f32x4 vacc0 = {0.f, 0.f, 0.f, 0.f};
        f32x4 vacc1 = {0.f, 0.f, 0.f, 0.f};
        #pragma unroll
        for (int k = lane; k < VEC4; k += 128) {
            f32x4 xv0 = __builtin_nontemporal_load(x4 + k);        // streamed
            f32x4 wv0 = w4[k];                                     // L1-resident
            f32x4 xv1 = __builtin_nontemporal_load(x4 + k + 64);
            f32x4 wv1 = w4[k + 64];
            vacc0 += xv0 * wv0;    // -ffp-contract=fast -> 2x v_pk_fma_f32
            vacc1 += xv1 * wv1;
        }
        f32x4 v = vacc0 + vacc1;
        float acc = (v.x + v.z) + (v.y + v.w);

        // wave-64 butterfly reduction
        #pragma unroll
        for (int off = 32; off > 0; off >>= 1) {
            acc += __shfl_xor(acc, off, 64);
        }

        if (lane == 0) {
            out[row] = tanhf(tanhf(acc + bias));
        }
    }
}

extern "C" void kernel_launch(void* const* d_in, const int* in_sizes, int n_in,
                              void* d_out, int out_size, void* d_ws, size_t ws_size,
                              hipStream_t stream) {
    const float* x = (const float*)d_in[0];
    const float* w = (const float*)d_in[1];
    const float* b = (const float*)d_in[2];
    float* out = (float*)d_out;

    cartnn_matvec_tanh<<<dim3(NBLOCKS), dim3(256), 0, stream>>>(x, w, b, out);
}